// Round 11
// baseline (15411.288 us; speedup 1.0000x reference)
//
#include <hip/hip_runtime.h>
#include <hip/hip_bf16.h>
#include <cstdint>
#include <cstddef>

#define Bdim 256
#define Tdim 256
#define Idim 512
#define Hdim 1024
#define Odim 5
#define BH (Bdim * Hdim)
#define BI (Bdim * Idim)

using short8 = __attribute__((ext_vector_type(8))) short;
using f32x4  = __attribute__((ext_vector_type(4))) float;
typedef unsigned long long u64;

__device__ __forceinline__ short bf16_of(float f) {
  unsigned u = __builtin_bit_cast(unsigned, f);
  u += 0x7fffu + ((u >> 16) & 1u);
  return (short)(u >> 16);
}

__device__ __forceinline__ float sigmf(float x) {
  return 1.0f / (1.0f + __expf(-x));
}

// flat fp32 -> bf16 (weights; [4,H,K] flattens to row-major [4H][K])
__global__ __launch_bounds__(256) void k_cvt_bf16(const float* __restrict__ src,
                                                  short* __restrict__ dst, int n) {
  int i0 = (blockIdx.x * 256 + threadIdx.x) * 8;
  int stride = gridDim.x * 256 * 8;
  for (int i = i0; i < n; i += stride) {
    float4 u = *reinterpret_cast<const float4*>(src + i);
    float4 v = *reinterpret_cast<const float4*>(src + i + 4);
    short8 o = {bf16_of(u.x), bf16_of(u.y), bf16_of(u.z), bf16_of(u.w),
                bf16_of(v.x), bf16_of(v.y), bf16_of(v.z), bf16_of(v.w)};
    *reinterpret_cast<short8*>(dst + i) = o;
  }
}

// x fp32 [B][T][I] -> bf16 [T][B][I]
__global__ __launch_bounds__(256) void k_cvt_x(const float* __restrict__ src,
                                               short* __restrict__ dst) {
  int e = (blockIdx.x * 256 + threadIdx.x) * 8;
  int row = e >> 9;
  int i0  = e & 511;
  int b = row >> 8, t = row & 255;
  float4 u = *reinterpret_cast<const float4*>(src + e);
  float4 v = *reinterpret_cast<const float4*>(src + e + 4);
  short8 o = {bf16_of(u.x), bf16_of(u.y), bf16_of(u.z), bf16_of(u.w),
              bf16_of(v.x), bf16_of(v.y), bf16_of(v.z), bf16_of(v.w)};
  *reinterpret_cast<short8*>(dst + (((t << 8) + b) << 9) + i0) = o;
}

__global__ __launch_bounds__(256) void k_init(const float* __restrict__ hidden,
    short* __restrict__ h0s0, short* __restrict__ h1s0) {
  int i = blockIdx.x * 256 + threadIdx.x;
  if (i < BH) {
    h0s0[i] = bf16_of(hidden[i]);
    h1s0[i] = bf16_of(hidden[2 * BH + i]);
  }
}

// split-group barrier: 2 layer-groups x 8 counters; 16 WGs arrive per counter
__device__ __forceinline__ void ctr_arrive(unsigned* ctr, int c) {
  __builtin_amdgcn_sched_barrier(0);
  __syncthreads();   // drains vmcnt(0): all agent-scope h-stores at MALL
  if (threadIdx.x == 0)
    __hip_atomic_fetch_add(&ctr[c * 32], 1u, __ATOMIC_RELAXED,
                           __HIP_MEMORY_SCOPE_AGENT);
}

__device__ __forceinline__ void ctr_poll2(unsigned* ctr, unsigned tg0, unsigned tg1) {
  if (threadIdx.x < 64) {
    const int lane = threadIdx.x;
    const unsigned tgt = (lane < 8) ? tg0 : (lane < 16 ? tg1 : 0u);
    unsigned* p = ctr + (lane < 16 ? lane : 0) * 32;
    for (;;) {
      bool ok = true;
      if (tgt) {
        unsigned v = __hip_atomic_load(p, __ATOMIC_RELAXED, __HIP_MEMORY_SCOPE_AGENT);
        ok = (v >= tgt);
      }
      if (__all(ok)) break;
      __builtin_amdgcn_s_sleep(1);
    }
  }
}

// DMA-stage one 128-k super (32 rows x 128 k bf16 = 8KB) into this wave's
// private LDS buffer. LDS layout [16 kb][32 row][8 elems]; instr j covers
// kb {2j, 2j+1}: lane l -> row l&31, kb j*2+(l>>5). Dest uniform per instr.
__device__ __forceinline__ void stage_super(short* sb, const short* g, int rs, int l) {
  #pragma unroll
  for (int j = 0; j < 8; ++j) {
    const int row = l & 31;
    const int kb  = j * 2 + (l >> 5);
    const short* src = g + (size_t)row * rs + kb * 8;
    __builtin_amdgcn_global_load_lds(
        (const __attribute__((address_space(1))) unsigned int*)(const void*)src,
        (__attribute__((address_space(3))) unsigned int*)(void*)(sb + j * 512),
        16, 0, 0);
  }
}

// Persistent weight-stationary LSTM. 256 WGs x 512 thr (1/CU).
// WG<128: L0 (8 h-cols); WG>=128: L1. Round r == timestep r for both layers.
// A-path: wave-private global_load_lds 2-buf pipeline (no K-loop barriers).
// B-path: bf16 weights from global, register double-buffered per 128-k super.
__global__ __launch_bounds__(512, 1) void k_persist(
    const short* __restrict__ W0b,    // [4H][1536] bf16
    const short* __restrict__ W1b,    // [4H][2048] bf16
    const float* __restrict__ b0v, const float* __restrict__ b1v,
    const float* __restrict__ hidden,
    const float* __restrict__ xf,     // fp32 [B][T][I] (fallback)
    const short* __restrict__ xbt,    // bf16 [T][B][I] (preferred)
    int useXb,
    short* __restrict__ h0seq,        // [D][B][H] bf16
    short* __restrict__ h1seq,        // [D][B][H] bf16
    float* __restrict__ finals,       // [L][2][B][H] fp32 (in d_out)
    unsigned* __restrict__ ctr, int D) {
  extern __shared__ short lw[];       // [8 waves][2 bufs][4096 shorts] = 128KB
  const int tid  = threadIdx.x;
  const int wg   = blockIdx.x;
  const bool isL0 = (wg < 128);
  const int slot  = isL0 ? wg : wg - 128;
  const int hcol0 = slot * 8;
  const int K     = isL0 ? (Hdim + Idim) : (2 * Hdim);
  const int layer = isL0 ? 0 : 1;
  const int myc   = layer * 8 + (wg & 7);
  const int lead  = D - 2;
  const short* Wb = isL0 ? W0b : W1b;
  const float* bsrc = isL0 ? b0v : b1v;

  const int lane = tid & 63;
  const int wv   = tid >> 6;
  const int col  = lane & 15;
  const int rg   = lane >> 4;
  const int kl   = rg * 8;
  const int wv32 = wv * 32;

  // global bf16 weight rows for this lane's two N-tiles
  // tile0 rows 0..15 = gates f(h0..7),i(h0..7); tile1 = g,o
  const short* wrow0 = Wb + (size_t)((col >> 3) * Hdim + hcol0 + (col & 7)) * K;
  const short* wrow1 = Wb + (size_t)((2 + (col >> 3)) * Hdim + hcol0 + (col & 7)) * K;

  float biasv[2];
  #pragma unroll
  for (int n = 0; n < 2; ++n)
    biasv[n] = bsrc[(n * 2 + (col >= 8 ? 1 : 0)) * Hdim + hcol0 + (col & 7)];

  float creg[2][4], hfin[2][4];
  #pragma unroll
  for (int m = 0; m < 2; ++m)
    #pragma unroll
    for (int j = 0; j < 4; ++j) {
      int b = wv32 + m * 16 + rg * 4 + j;
      creg[m][j] = hidden[(layer * 2 + 1) * BH + b * Hdim + hcol0 + (col & 7)];
      hfin[m][j] = 0.f;
    }

  // launch-start acquire: one L2/L1 inv per WG per launch (replay staleness)
  if (tid == 0)
    (void)__hip_atomic_load(ctr, __ATOMIC_ACQUIRE, __HIP_MEMORY_SCOPE_AGENT);
  __syncthreads();

  short* ab0 = lw + wv * 8192;        // per-wave private A buffers
  short* ab1 = ab0 + 4096;

  int i_cur = 0;
  for (int r = 0; r < 256; ++r) {
    const int i_next = (i_cur + 1 == D) ? 0 : i_cur + 1;

    // ---- sync (single poll per round) ----
    if (isL0) {
      unsigned tg1 = (r > lead) ? 16u * (unsigned)(r - lead) : 0u;  // throttle
      if (r > 0 || tg1) ctr_poll2(ctr, (r > 0) ? 16u * (unsigned)r : 0u, tg1);
    } else {
      ctr_poll2(ctr, 16u * (unsigned)(r + 1), (r > 0) ? 16u * (unsigned)r : 0u);
    }
    if (tid == 0 && r > 0 && (i_cur == 0 || i_next == 0))  // wrap inv
      (void)__hip_atomic_load(ctr, __ATOMIC_ACQUIRE, __HIP_MEMORY_SCOPE_AGENT);
    __syncthreads();

    // ---- DMA-pipelined GEMM over NS supers of 128 k ----
    const int NS = isL0 ? (useXb ? 12 : 8) : 16;
    const short* sA = (isL0 ? h0seq + (size_t)i_cur * BH
                            : h1seq + (size_t)i_cur * BH) + (size_t)wv32 * Hdim;
    const short* sX = isL0 ? (useXb ? xbt + (size_t)r * BI + (size_t)wv32 * Idim
                                    : (const short*)nullptr)
                           : h0seq + (size_t)i_next * BH + (size_t)wv32 * Hdim;
    const int rsX = isL0 ? Idim : Hdim;

    f32x4 acc[2][2] = {};
    short8 Bc0[4], Bc1[4], Bn0[4], Bn1[4];

    stage_super(ab0, sA, Hdim, lane);
    stage_super(ab1, sA + 128, Hdim, lane);
    #pragma unroll
    for (int t = 0; t < 4; ++t) {
      Bc0[t] = *(const short8*)(wrow0 + t * 32 + kl);
      Bc1[t] = *(const short8*)(wrow1 + t * 32 + kl);
    }

    for (int s = 0; s < NS; ++s) {
      // stage(s) guaranteed complete: per-iter VMEM = 8 glds + 8 B-loads,
      // pinned across iterations by the volatile memory-clobber waitcnt.
      if (s == NS - 1) { asm volatile("s_waitcnt vmcnt(8)" ::: "memory"); }
      else             { asm volatile("s_waitcnt vmcnt(16)" ::: "memory"); }
      __builtin_amdgcn_sched_barrier(0);

      if (s + 1 < NS) {                 // B for next super (register dbuf)
        const int kg = (s + 1) * 128 + kl;
        #pragma unroll
        for (int t = 0; t < 4; ++t) {
          Bn0[t] = *(const short8*)(wrow0 + kg + t * 32);
          Bn1[t] = *(const short8*)(wrow1 + kg + t * 32);
        }
      }

      const short* sb = (s & 1) ? ab1 : ab0;
      #pragma unroll
      for (int t = 0; t < 4; ++t) {     // 4 k-steps of 32
        const short8 a0 = *(const short8*)(sb + (t * 4 + rg) * 256 + col * 8);
        const short8 a1 = *(const short8*)(sb + (t * 4 + rg) * 256 + (16 + col) * 8);
        acc[0][0] = __builtin_amdgcn_mfma_f32_16x16x32_bf16(a0, Bc0[t], acc[0][0], 0, 0, 0);
        acc[1][0] = __builtin_amdgcn_mfma_f32_16x16x32_bf16(a1, Bc0[t], acc[1][0], 0, 0, 0);
        acc[0][1] = __builtin_amdgcn_mfma_f32_16x16x32_bf16(a0, Bc1[t], acc[0][1], 0, 0, 0);
        acc[1][1] = __builtin_amdgcn_mfma_f32_16x16x32_bf16(a1, Bc1[t], acc[1][1], 0, 0, 0);
      }

      // all ds_reads of this buffer retired before re-staging into it
      asm volatile("s_waitcnt lgkmcnt(0)" ::: "memory");
      __builtin_amdgcn_sched_barrier(0);
      if (s + 2 < NS) {
        const int sn = s + 2;
        const short* g = (sn < 8) ? sA + sn * 128 : sX + (sn - 8) * 128;
        stage_super((s & 1) ? ab1 : ab0, g, (sn < 8) ? Hdim : rsX, lane);
      }
      #pragma unroll
      for (int t = 0; t < 4; ++t) { Bc0[t] = Bn0[t]; Bc1[t] = Bn1[t]; }
    }

    // fp32-x fallback tail (L0 only, if no xbt buffer)
    if (isL0 && !useXb) {
      const float* xf0 = xf + ((size_t)(wv32 + col) * Tdim + r) * Idim - Hdim;
      const float* xf1 = xf + ((size_t)(wv32 + 16 + col) * Tdim + r) * Idim - Hdim;
      for (int k0 = Hdim; k0 < K; k0 += 32) {
        int k = k0 + kl;
        short8 b0 = *(const short8*)(wrow0 + k);
        short8 b1 = *(const short8*)(wrow1 + k);
        f32x4 u0 = *(const f32x4*)(xf0 + k), u1 = *(const f32x4*)(xf0 + k + 4);
        f32x4 v0 = *(const f32x4*)(xf1 + k), v1 = *(const f32x4*)(xf1 + k + 4);
        short8 a0 = {bf16_of(u0[0]), bf16_of(u0[1]), bf16_of(u0[2]), bf16_of(u0[3]),
                     bf16_of(u1[0]), bf16_of(u1[1]), bf16_of(u1[2]), bf16_of(u1[3])};
        short8 a1 = {bf16_of(v0[0]), bf16_of(v0[1]), bf16_of(v0[2]), bf16_of(v0[3]),
                     bf16_of(v1[0]), bf16_of(v1[1]), bf16_of(v1[2]), bf16_of(v1[3])};
        acc[0][0] = __builtin_amdgcn_mfma_f32_16x16x32_bf16(a0, b0, acc[0][0], 0, 0, 0);
        acc[1][0] = __builtin_amdgcn_mfma_f32_16x16x32_bf16(a1, b0, acc[1][0], 0, 0, 0);
        acc[0][1] = __builtin_amdgcn_mfma_f32_16x16x32_bf16(a0, b1, acc[0][1], 0, 0, 0);
        acc[1][1] = __builtin_amdgcn_mfma_f32_16x16x32_bf16(a1, b1, acc[1][1], 0, 0, 0);
      }
    }

    // ---- fused gates (R9-verified): tile0=f/i, tile1=g/o ----
    short* hout = isL0 ? h0seq + (size_t)i_next * BH : h1seq + (size_t)i_next * BH;
    #pragma unroll
    for (int m = 0; m < 2; ++m) {
      #pragma unroll
      for (int j = 0; j < 4; ++j) {
        float fi  = acc[m][0][j] + biasv[0];
        float go  = acc[m][1][j] + biasv[1];
        float iv_ = __shfl_xor(fi, 8, 64);
        float ov_ = __shfl_xor(go, 8, 64);
        float fv = sigmf(fi), iv = sigmf(iv_);
        float gv = tanhf(go), ov = sigmf(ov_);
        float cn = fv * creg[m][j] + iv * gv;
        creg[m][j] = cn;
        float hn = ov * tanhf(cn);
        hfin[m][j] = hn;
        // pack 4 consecutive h-cols into one 8B agent-scope (MALL) store
        unsigned hv = (unsigned)(unsigned short)bf16_of(hn);
        unsigned p1 = hv | ((unsigned)__shfl_xor((int)hv, 1, 64) << 16);
        u64 p2 = (u64)p1 | ((u64)(unsigned)__shfl_xor((int)p1, 2, 64) << 32);
        if ((col & 3) == 0 && col < 8) {
          int b = wv32 + m * 16 + rg * 4 + j;
          __hip_atomic_store((u64*)(hout + b * Hdim + hcol0 + col), p2,
                             __ATOMIC_RELAXED, __HIP_MEMORY_SCOPE_AGENT);
        }
      }
    }
    ctr_arrive(ctr, myc);
    i_cur = i_next;
  }

  // epilogue: finals [L][2][B][H]; lanes col<8 own h-col hcol0+col
  if (col < 8) {
    #pragma unroll
    for (int m = 0; m < 2; ++m)
      #pragma unroll
      for (int j = 0; j < 4; ++j) {
        int b = wv32 + m * 16 + rg * 4 + j;
        finals[(layer * 2 + 0) * BH + b * Hdim + hcol0 + col] = hfin[m][j];
        finals[(layer * 2 + 1) * BH + b * Hdim + hcol0 + col] = creg[m][j];
      }
  }
}

__global__ __launch_bounds__(256) void k_outproj(const float* __restrict__ h1f,
    const float* __restrict__ Wout, const float* __restrict__ bout,
    float* __restrict__ out) {
  int b = blockIdx.x;
  int tid = threadIdx.x;
  float hv[4];
  #pragma unroll
  for (int j = 0; j < 4; ++j) hv[j] = h1f[b * Hdim + tid + j * 256];
  __shared__ float red[Odim][4];
  #pragma unroll
  for (int o = 0; o < Odim; ++o) {
    float p = 0.f;
    #pragma unroll
    for (int j = 0; j < 4; ++j) p += hv[j] * Wout[o * Hdim + tid + j * 256];
    #pragma unroll
    for (int s = 32; s > 0; s >>= 1) p += __shfl_down(p, s, 64);
    if ((tid & 63) == 0) red[o][tid >> 6] = p;
  }
  __syncthreads();
  if (tid < Odim)
    out[b * Odim + tid] = red[tid][0] + red[tid][1] + red[tid][2] + red[tid][3] + bout[tid];
}

extern "C" void kernel_launch(void* const* d_in, const int* in_sizes, int n_in,
                              void* d_out, int out_size, void* d_ws, size_t ws_size,
                              hipStream_t stream) {
  const float* x      = (const float*)d_in[0];
  const float* hidden = (const float*)d_in[1];
  const float* W0     = (const float*)d_in[2];
  const float* b0     = (const float*)d_in[3];
  const float* W1     = (const float*)d_in[4];
  const float* b1     = (const float*)d_in[5];
  const float* Wout   = (const float*)d_in[6];
  const float* bout   = (const float*)d_in[7];
  float* out = (float*)d_out;
  float* finals = out + Bdim * Odim;

  char* ws = (char*)d_ws;
  size_t off = 0;
  auto alloc = [&](size_t bytes) {
    void* p = ws + off;
    off += (bytes + 255) & ~(size_t)255;
    return p;
  };
  unsigned* ctr = (unsigned*)alloc(16 * 32 * sizeof(unsigned));
  short* W0b = (short*)alloc((size_t)4096 * 1536 * 2);       // 12.6 MB
  short* W1b = (short*)alloc((size_t)4096 * 2048 * 2);       // 16.8 MB
  const size_t seqSlot = (size_t)BH * 2;                     // 0.5 MB
  const size_t xbBytes = (size_t)Tdim * Bdim * Idim * 2;     // 67.1 MB
  int useXb = 0;
  short* xbt = nullptr;
  if (ws_size > off + xbBytes + 8 * 2 * seqSlot + (1 << 20)) {
    useXb = 1;
    xbt = (short*)alloc(xbBytes);
  }
  size_t avail = (ws_size > off + 512) ? (ws_size - off - 512) : 0;
  int D = (int)(avail / (2 * seqSlot));
  if (D > 64) D = 64;
  if (D < 4) D = 4;
  short* h0seq = (short*)alloc((size_t)D * seqSlot);
  short* h1seq = (short*)alloc((size_t)D * seqSlot);

  k_cvt_bf16<<<2048, 256, 0, stream>>>(W0, W0b, 4096 * 1536);
  k_cvt_bf16<<<2048, 256, 0, stream>>>(W1, W1b, 4096 * 2048);
  if (useXb)
    k_cvt_x<<<(Tdim * Bdim * Idim) / (256 * 8), 256, 0, stream>>>(x, xbt);
  k_init<<<BH / 256, 256, 0, stream>>>(hidden, h0seq, h1seq);
  hipMemsetAsync(ctr, 0, 16 * 32 * sizeof(unsigned), stream);

  const int ldsBytes = 8 * 2 * 4096 * 2;  // 131072: 8 waves x 2 bufs x 8KB
  hipFuncSetAttribute((const void*)k_persist,
                      hipFuncAttributeMaxDynamicSharedMemorySize, ldsBytes);
  void* args[] = {(void*)&W0b, (void*)&W1b, (void*)&b0, (void*)&b1,
                  (void*)&hidden, (void*)&x, (void*)&xbt, (void*)&useXb,
                  (void*)&h0seq, (void*)&h1seq,
                  (void*)&finals, (void*)&ctr, (void*)&D};
  hipLaunchCooperativeKernel((const void*)k_persist, dim3(256), dim3(512),
                             args, ldsBytes, stream);

  k_outproj<<<Bdim, 256, 0, stream>>>(finals + 2 * BH, Wout, bout, out);
}

// Round 13
// 10929.779 us; speedup vs baseline: 1.4100x; 1.4100x over previous
//
#include <hip/hip_runtime.h>
#include <hip/hip_bf16.h>
#include <cstdint>
#include <cstddef>

#define Bdim 256
#define Tdim 256
#define Idim 512
#define Hdim 1024
#define Odim 5
#define BH (Bdim * Hdim)
#define BI (Bdim * Idim)

using short8 = __attribute__((ext_vector_type(8))) short;
using f32x4  = __attribute__((ext_vector_type(4))) float;
typedef unsigned long long u64;

__device__ __forceinline__ short bf16_of(float f) {
  unsigned u = __builtin_bit_cast(unsigned, f);
  u += 0x7fffu + ((u >> 16) & 1u);
  return (short)(u >> 16);
}

__device__ __forceinline__ float sigmf(float x) {
  return 1.0f / (1.0f + __expf(-x));
}

__global__ __launch_bounds__(256) void k_cvt_bf16(const float* __restrict__ src,
                                                  short* __restrict__ dst, int n) {
  int i0 = (blockIdx.x * 256 + threadIdx.x) * 8;
  int stride = gridDim.x * 256 * 8;
  for (int i = i0; i < n; i += stride) {
    float4 u = *reinterpret_cast<const float4*>(src + i);
    float4 v = *reinterpret_cast<const float4*>(src + i + 4);
    short8 o = {bf16_of(u.x), bf16_of(u.y), bf16_of(u.z), bf16_of(u.w),
                bf16_of(v.x), bf16_of(v.y), bf16_of(v.z), bf16_of(v.w)};
    *reinterpret_cast<short8*>(dst + i) = o;
  }
}

// x fp32 [B][T][I] -> bf16 [T][B][I]
__global__ __launch_bounds__(256) void k_cvt_x(const float* __restrict__ src,
                                               short* __restrict__ dst) {
  int e = (blockIdx.x * 256 + threadIdx.x) * 8;
  int row = e >> 9;
  int i0  = e & 511;
  int b = row >> 8, t = row & 255;
  float4 u = *reinterpret_cast<const float4*>(src + e);
  float4 v = *reinterpret_cast<const float4*>(src + e + 4);
  short8 o = {bf16_of(u.x), bf16_of(u.y), bf16_of(u.z), bf16_of(u.w),
              bf16_of(v.x), bf16_of(v.y), bf16_of(v.z), bf16_of(v.w)};
  *reinterpret_cast<short8*>(dst + (((t << 8) + b) << 9) + i0) = o;
}

__global__ __launch_bounds__(256) void k_init(const float* __restrict__ hidden,
    short* __restrict__ h0s0, short* __restrict__ h1s0) {
  int i = blockIdx.x * 256 + threadIdx.x;
  if (i < BH) {
    h0s0[i] = bf16_of(hidden[i]);
    h1s0[i] = bf16_of(hidden[2 * BH + i]);
  }
}

// arrive: syncthreads (drains stores to MALL) + one relaxed agent RMW
__device__ __forceinline__ void ctr_arrive(unsigned* ctr, int c) {
  __builtin_amdgcn_sched_barrier(0);
  __syncthreads();
  if (threadIdx.x == 0)
    __hip_atomic_fetch_add(&ctr[c * 32], 1u, __ATOMIC_RELAXED,
                           __HIP_MEMORY_SCOPE_AGENT);
}

// per-WAVE poll (all waves execute; no cross-wave barrier needed after)
__device__ __forceinline__ void poll_wave(unsigned* ctr, unsigned tg0,
                                          unsigned tg1, int lane) {
  const unsigned tgt = (lane < 8) ? tg0 : (lane < 16 ? tg1 : 0u);
  unsigned* p = ctr + (lane & 15) * 32;
  for (;;) {
    bool ok = true;
    if (tgt) {
      unsigned v = __hip_atomic_load(p, __ATOMIC_RELAXED, __HIP_MEMORY_SCOPE_AGENT);
      ok = (v >= tgt);
    }
    if (__all(ok)) break;
    __builtin_amdgcn_s_sleep(1);
  }
}

// cooperative stage of super S (32KB = [16 kb][128 batch][8]) into buf S%3.
// DMA dest is LINEAR (wave-uniform base + lane*16B); the batch<->slot XOR
// swizzle is applied on the per-lane GLOBAL source (m173 pattern) and undone
// on the read side -> 2-way max bank aliasing (free).
#define STAGE(S, SRC, RS)                                                      \
  { short* _d = lw + ((S) % 3) * 16384;                                        \
    const short* _s = (SRC);                                                   \
    _Pragma("unroll")                                                          \
    for (int j = 0; j < 8; ++j) {                                              \
      const int kb = (wv >> 1) * 8 + j;                                        \
      const int srow = ((wv & 1) * 64 + lane) ^ (kb & 7);                      \
      __builtin_amdgcn_global_load_lds(                                        \
        (const __attribute__((address_space(1))) unsigned*)(const void*)       \
          (_s + (size_t)srow * (RS) + kb * 8),                                 \
        (__attribute__((address_space(3))) unsigned*)(void*)                   \
          (_d + (kb * 128 + (wv & 1) * 64) * 8),                               \
        16, 0, 0);                                                             \
    } }

#define WAITV(N) do { asm volatile("s_waitcnt vmcnt(" #N ")" ::: "memory");    \
                      __builtin_amdgcn_sched_barrier(0); } while (0)
#define SBAR()   asm volatile("s_barrier" ::: "memory")

// compute super (buf BI_), Wreg base KB4: 32 ds_read_b128 + 32 MFMA
#define COMP(BI_, KB4)                                                         \
  { const short* _ab = lw + (BI_) * 16384;                                     \
    _Pragma("unroll")                                                          \
    for (int t = 0; t < 4; ++t) {                                              \
      const int _kb = t * 4 + rg;                                              \
      const short* _as = _ab + _kb * 1024;                                     \
      _Pragma("unroll")                                                        \
      for (int m = 0; m < 8; ++m) {                                            \
        short8 a = *(const short8*)(_as + (((m * 16 + col) ^ (_kb & 7)) * 8)); \
        acc[m] = __builtin_amdgcn_mfma_f32_16x16x32_bf16(a, Wreg[(KB4) + t],   \
                                                         acc[m], 0, 0, 0);     \
      } } }

#define ITER(S, KB4, WN) WAITV(WN); SBAR(); COMP((S) % 3, KB4); SBAR()

// Persistent LSTM: 256 WGs x 256 thr (4 waves = 4 gates), 1 WG/CU.
// WG = (layer, hslice 0..63 [16 hcols], batch-half 0..1 [128 rows]).
// Weights: register-stationary per wave (full K). A: shared LDS DMA staging.
// gf (gate recombine buffer) ALIASES A-buf0 — only live between last ITER's
// s_barrier and ctr_arrive's syncthreads, when buf0 has no readers/writers.
__global__ __launch_bounds__(256, 1) void k_persist(
    const short* __restrict__ W0b,    // [4H][1536] bf16
    const short* __restrict__ W1b,    // [4H][2048] bf16
    const float* __restrict__ b0v, const float* __restrict__ b1v,
    const float* __restrict__ hidden,
    const float* __restrict__ xf,     // fp32 [B][T][I] (fallback)
    const short* __restrict__ xbt,    // bf16 [T][B][I] (preferred)
    int useXb,
    short* __restrict__ h0seq, short* __restrict__ h1seq,  // [D][B][H]
    float* __restrict__ finals,       // [L][2][B][H] fp32 (in d_out)
    unsigned* __restrict__ ctr, int D) {
  extern __shared__ short lw[];       // 3 x 16384 shorts (A bufs; buf0 = gf)
  float* gf = (float*)lw;             // [4][128][16] f32 gate preacts (alias)
  const int tid  = threadIdx.x;
  const int wg   = blockIdx.x;
  const bool isL0 = (wg < 128);
  const int sub   = isL0 ? wg : wg - 128;
  const int hsl   = sub >> 1;
  const int bhalf = sub & 1;
  const int hcol0 = hsl * 16;
  const int batch0 = bhalf * 128;
  const int K     = isL0 ? (Hdim + Idim) : (2 * Hdim);
  const int layer = isL0 ? 0 : 1;
  const int myc   = layer * 8 + (wg & 7);
  const int lead  = D - 2;
  const short* Wb = isL0 ? W0b : W1b;
  const float* bsrc = isL0 ? b0v : b1v;

  const int lane = tid & 63;
  const int wv   = tid >> 6;          // wave index == gate (0=f,1=i,2=g,3=o)
  const int col  = lane & 15;
  const int rg   = lane >> 4;

  // ---- register-stationary weights: 16 rows (gate wv, hcols hcol0..+15) ----
  short8 Wreg[64];
  { const short* wr = Wb + (size_t)(wv * Hdim + hcol0 + col) * K + rg * 8;
    if (isL0) {
      #pragma unroll
      for (int st = 0; st < 48; ++st) Wreg[st] = *(const short8*)(wr + st * 32);
    } else {
      #pragma unroll
      for (int st = 0; st < 64; ++st) Wreg[st] = *(const short8*)(wr + st * 32);
    } }

  const float biasv = bsrc[wv * Hdim + hcol0 + col];

  // ---- per-thread recombine state: 8 cells (batch bl=tid>>1, hcols hc0..+8)
  const int bl  = tid >> 1;
  const int hc0 = (tid & 1) * 8;
  float creg[8], hfin[8];
  { const float* cs = hidden + (size_t)(layer * 2 + 1) * BH
                      + (size_t)(batch0 + bl) * Hdim + hcol0 + hc0;
    #pragma unroll
    for (int e = 0; e < 8; ++e) { creg[e] = cs[e]; hfin[e] = 0.f; } }

  if (tid == 0)
    (void)__hip_atomic_load(ctr, __ATOMIC_ACQUIRE, __HIP_MEMORY_SCOPE_AGENT);
  __syncthreads();

  int i_cur = 0;
  for (int r = 0; r < 256; ++r) {
    const int i_next = (i_cur + 1 == D) ? 0 : i_cur + 1;

    // ---- sync: every wave polls independently ----
    if (isL0) {
      unsigned tg1 = (r > lead) ? 16u * (unsigned)(r - lead) : 0u;
      if (r > 0 || tg1) poll_wave(ctr, (r > 0) ? 16u * (unsigned)r : 0u, tg1, lane);
    } else {
      poll_wave(ctr, 16u * (unsigned)(r + 1), (r > 0) ? 16u * (unsigned)r : 0u, lane);
    }
    if (lane == 0 && r > 0 && (i_cur == 0 || i_next == 0))  // wrap inv, per wave
      (void)__hip_atomic_load(ctr, __ATOMIC_ACQUIRE, __HIP_MEMORY_SCOPE_AGENT);

    f32x4 acc[8] = {};

    if (isL0) {
      const short* hb = h0seq + (size_t)i_cur * BH + (size_t)batch0 * Hdim;
      STAGE(0, hb + 0 * 128, Hdim)
      STAGE(1, hb + 1 * 128, Hdim)
      STAGE(2, hb + 2 * 128, Hdim)
      if (useXb) {
        const short* xb = xbt + (size_t)r * BI + (size_t)batch0 * Idim;
        ITER(0, 0, 16);  STAGE(3, hb + 3 * 128, Hdim)
        ITER(1, 4, 16);  STAGE(4, hb + 4 * 128, Hdim)
        ITER(2, 8, 16);  STAGE(5, hb + 5 * 128, Hdim)
        ITER(3, 12, 16); STAGE(6, hb + 6 * 128, Hdim)
        ITER(4, 16, 16); STAGE(7, hb + 7 * 128, Hdim)
        ITER(5, 20, 16); STAGE(8, xb + 0 * 128, Idim)
        ITER(6, 24, 16); STAGE(9, xb + 1 * 128, Idim)
        ITER(7, 28, 16); STAGE(10, xb + 2 * 128, Idim)
        ITER(8, 32, 16); STAGE(11, xb + 3 * 128, Idim)
        ITER(9, 36, 16);
        ITER(10, 40, 8);
        ITER(11, 44, 0);
      } else {
        ITER(0, 0, 16);  STAGE(3, hb + 3 * 128, Hdim)
        ITER(1, 4, 16);  STAGE(4, hb + 4 * 128, Hdim)
        ITER(2, 8, 16);  STAGE(5, hb + 5 * 128, Hdim)
        ITER(3, 12, 16); STAGE(6, hb + 6 * 128, Hdim)
        ITER(4, 16, 16); STAGE(7, hb + 7 * 128, Hdim)
        ITER(5, 20, 16);
        ITER(6, 24, 8);
        ITER(7, 28, 0);
        // fp32 x tail: k-steps 32..47
        const float* xrow[8];
        #pragma unroll
        for (int m = 0; m < 8; ++m)
          xrow[m] = xf + ((size_t)(batch0 + m * 16 + col) * Tdim + r) * Idim + rg * 8;
        #pragma unroll
        for (int st = 32; st < 48; ++st) {
          #pragma unroll
          for (int m = 0; m < 8; ++m) {
            const float* p = xrow[m] + (st - 32) * 32;
            f32x4 u = *(const f32x4*)p, v = *(const f32x4*)(p + 4);
            short8 a = {bf16_of(u[0]), bf16_of(u[1]), bf16_of(u[2]), bf16_of(u[3]),
                        bf16_of(v[0]), bf16_of(v[1]), bf16_of(v[2]), bf16_of(v[3])};
            acc[m] = __builtin_amdgcn_mfma_f32_16x16x32_bf16(a, Wreg[st], acc[m], 0, 0, 0);
          }
        }
      }
    } else {
      const short* hb = h1seq + (size_t)i_cur * BH + (size_t)batch0 * Hdim;
      const short* xb = h0seq + (size_t)i_next * BH + (size_t)batch0 * Hdim;
      STAGE(0, hb + 0 * 128, Hdim)
      STAGE(1, hb + 1 * 128, Hdim)
      STAGE(2, hb + 2 * 128, Hdim)
      ITER(0, 0, 16);  STAGE(3, hb + 3 * 128, Hdim)
      ITER(1, 4, 16);  STAGE(4, hb + 4 * 128, Hdim)
      ITER(2, 8, 16);  STAGE(5, hb + 5 * 128, Hdim)
      ITER(3, 12, 16); STAGE(6, hb + 6 * 128, Hdim)
      ITER(4, 16, 16); STAGE(7, hb + 7 * 128, Hdim)
      ITER(5, 20, 16); STAGE(8, xb + 0 * 128, Hdim)
      ITER(6, 24, 16); STAGE(9, xb + 1 * 128, Hdim)
      ITER(7, 28, 16); STAGE(10, xb + 2 * 128, Hdim)
      ITER(8, 32, 16); STAGE(11, xb + 3 * 128, Hdim)
      ITER(9, 36, 16); STAGE(12, xb + 4 * 128, Hdim)
      ITER(10, 40, 16); STAGE(13, xb + 5 * 128, Hdim)
      ITER(11, 44, 16); STAGE(14, xb + 6 * 128, Hdim)
      ITER(12, 48, 16); STAGE(15, xb + 7 * 128, Hdim)
      ITER(13, 52, 16);
      ITER(14, 56, 8);
      ITER(15, 60, 0);
    }

    // ---- stage gate preacts (wave = gate) into gf (aliases buf0) ----
    // Safe: last ITER ended with s_barrier (all DMA retired, all reads done).
    #pragma unroll
    for (int m = 0; m < 8; ++m)
      #pragma unroll
      for (int j = 0; j < 4; ++j)
        gf[(wv * 128 + m * 16 + rg * 4 + j) * 16 + col] = acc[m][j] + biasv;
    __syncthreads();

    // ---- recombine: thread owns 8 cells, c in regs, h packed 2x u64 ----
    {
      const int go = bl * 16 + hc0;
      f32x4 F0 = *(const f32x4*)(gf + go),          F1 = *(const f32x4*)(gf + go + 4);
      f32x4 I0 = *(const f32x4*)(gf + 2048 + go),   I1 = *(const f32x4*)(gf + 2048 + go + 4);
      f32x4 G0 = *(const f32x4*)(gf + 4096 + go),   G1 = *(const f32x4*)(gf + 4096 + go + 4);
      f32x4 O0 = *(const f32x4*)(gf + 6144 + go),   O1 = *(const f32x4*)(gf + 6144 + go + 4);
      unsigned short hb16[8];
      #pragma unroll
      for (int e = 0; e < 8; ++e) {
        float fv = sigmf(e < 4 ? F0[e] : F1[e - 4]);
        float iv = sigmf(e < 4 ? I0[e] : I1[e - 4]);
        float gv = tanhf(e < 4 ? G0[e] : G1[e - 4]);
        float ov = sigmf(e < 4 ? O0[e] : O1[e - 4]);
        float cn = fv * creg[e] + iv * gv;
        creg[e] = cn;
        float hn = ov * tanhf(cn);
        hfin[e] = hn;
        hb16[e] = (unsigned short)bf16_of(hn);
      }
      short* hout = (isL0 ? h0seq : h1seq) + (size_t)i_next * BH
                    + (size_t)(batch0 + bl) * Hdim + hcol0 + hc0;
      u64 plo = (u64)hb16[0] | ((u64)hb16[1] << 16) | ((u64)hb16[2] << 32) | ((u64)hb16[3] << 48);
      u64 phi = (u64)hb16[4] | ((u64)hb16[5] << 16) | ((u64)hb16[6] << 32) | ((u64)hb16[7] << 48);
      __hip_atomic_store((u64*)hout, plo, __ATOMIC_RELAXED, __HIP_MEMORY_SCOPE_AGENT);
      __hip_atomic_store((u64*)(hout + 4), phi, __ATOMIC_RELAXED, __HIP_MEMORY_SCOPE_AGENT);
    }
    ctr_arrive(ctr, myc);
    i_cur = i_next;
  }

  // ---- epilogue: finals [L][2][B][H] ----
  {
    float* fh = finals + (size_t)(layer * 2) * BH + (size_t)(batch0 + bl) * Hdim + hcol0 + hc0;
    float* fc = fh + BH;
    *(float4*)fh = make_float4(hfin[0], hfin[1], hfin[2], hfin[3]);
    *(float4*)(fh + 4) = make_float4(hfin[4], hfin[5], hfin[6], hfin[7]);
    *(float4*)fc = make_float4(creg[0], creg[1], creg[2], creg[3]);
    *(float4*)(fc + 4) = make_float4(creg[4], creg[5], creg[6], creg[7]);
  }
}

__global__ __launch_bounds__(256) void k_outproj(const float* __restrict__ h1f,
    const float* __restrict__ Wout, const float* __restrict__ bout,
    float* __restrict__ out) {
  int b = blockIdx.x;
  int tid = threadIdx.x;
  float hv[4];
  #pragma unroll
  for (int j = 0; j < 4; ++j) hv[j] = h1f[b * Hdim + tid + j * 256];
  __shared__ float red[Odim][4];
  #pragma unroll
  for (int o = 0; o < Odim; ++o) {
    float p = 0.f;
    #pragma unroll
    for (int j = 0; j < 4; ++j) p += hv[j] * Wout[o * Hdim + tid + j * 256];
    #pragma unroll
    for (int s = 32; s > 0; s >>= 1) p += __shfl_down(p, s, 64);
    if ((tid & 63) == 0) red[o][tid >> 6] = p;
  }
  __syncthreads();
  if (tid < Odim)
    out[b * Odim + tid] = red[tid][0] + red[tid][1] + red[tid][2] + red[tid][3] + bout[tid];
}

extern "C" void kernel_launch(void* const* d_in, const int* in_sizes, int n_in,
                              void* d_out, int out_size, void* d_ws, size_t ws_size,
                              hipStream_t stream) {
  const float* x      = (const float*)d_in[0];
  const float* hidden = (const float*)d_in[1];
  const float* W0     = (const float*)d_in[2];
  const float* b0     = (const float*)d_in[3];
  const float* W1     = (const float*)d_in[4];
  const float* b1     = (const float*)d_in[5];
  const float* Wout   = (const float*)d_in[6];
  const float* bout   = (const float*)d_in[7];
  float* out = (float*)d_out;
  float* finals = out + Bdim * Odim;

  char* ws = (char*)d_ws;
  size_t off = 0;
  auto alloc = [&](size_t bytes) {
    void* p = ws + off;
    off += (bytes + 255) & ~(size_t)255;
    return p;
  };
  unsigned* ctr = (unsigned*)alloc(16 * 32 * sizeof(unsigned));
  short* W0b = (short*)alloc((size_t)4096 * 1536 * 2);
  short* W1b = (short*)alloc((size_t)4096 * 2048 * 2);
  const size_t seqSlot = (size_t)BH * 2;                     // 0.5 MB
  const size_t xbBytes = (size_t)Tdim * Bdim * Idim * 2;     // 67.1 MB
  int useXb = 0;
  short* xbt = nullptr;
  if (ws_size > off + xbBytes + 8 * 2 * seqSlot + (1 << 20)) {
    useXb = 1;
    xbt = (short*)alloc(xbBytes);
  }
  size_t avail = (ws_size > off + 512) ? (ws_size - off - 512) : 0;
  int D = (int)(avail / (2 * seqSlot));
  if (D > 64) D = 64;
  if (D < 4) D = 4;
  short* h0seq = (short*)alloc((size_t)D * seqSlot);
  short* h1seq = (short*)alloc((size_t)D * seqSlot);

  k_cvt_bf16<<<2048, 256, 0, stream>>>(W0, W0b, 4096 * 1536);
  k_cvt_bf16<<<2048, 256, 0, stream>>>(W1, W1b, 4096 * 2048);
  if (useXb)
    k_cvt_x<<<(Tdim * Bdim * Idim) / (256 * 8), 256, 0, stream>>>(x, xbt);
  k_init<<<BH / 256, 256, 0, stream>>>(hidden, h0seq, h1seq);
  hipMemsetAsync(ctr, 0, 16 * 32 * sizeof(unsigned), stream);

  const int ldsBytes = 3 * 32768;  // 98304 — proven-launchable range
  hipFuncSetAttribute((const void*)k_persist,
                      hipFuncAttributeMaxDynamicSharedMemorySize, ldsBytes);
  void* args[] = {(void*)&W0b, (void*)&W1b, (void*)&b0, (void*)&b1,
                  (void*)&hidden, (void*)&x, (void*)&xbt, (void*)&useXb,
                  (void*)&h0seq, (void*)&h1seq,
                  (void*)&finals, (void*)&ctr, (void*)&D};
  hipError_t ce = hipLaunchCooperativeKernel((const void*)k_persist,
                                             dim3(256), dim3(256),
                                             args, ldsBytes, stream);
  if (ce != hipSuccess) {
    // Fallback: plain launch. 256 blocks at 1 WG/CU on 256 CUs are de-facto
    // co-resident; sync uses raw atomics (no cooperative-groups API needed).
    k_persist<<<dim3(256), dim3(256), ldsBytes, stream>>>(
        W0b, W1b, b0, b1, hidden, x, xbt, useXb,
        h0seq, h1seq, finals, ctr, D);
  }

  k_outproj<<<Bdim, 256, 0, stream>>>(finals + 2 * BH, Wout, bout, out);
}